// Round 4
// baseline (268.811 us; speedup 1.0000x reference)
//
#include <hip/hip_runtime.h>

// CTC loss forward, T=1024, B=128, C=256, S=128, L=2S+1=257.
// One wave (64 lanes) per batch. Lane l owns odd states O[2l],O[2l+1]
// (labels y[2l],y[2l+1]) and blank states E[2l],E[2l+1]; E[128] kept
// LANE-LOCAL (only lane 63's copy is real; broadcast once at the end).
// Exp-domain recursion in FP64 with exact power-of-2 renorm every 8 steps.
//
// R4: pin the 16-deep register prefetch with RELAXED ATOMIC loads
// (workgroup scope -> plain global_load_dword, no cache-bypass bits).
// R3's counters proved the plain-load pipeline was DELETED at IR level
// (VGPR_Count=48 == no room for 48 prefetch floats): for const __restrict__
// memory the compiler may rematerialize a load at its use, so it sank every
// load to its consumer and exposed ~175cy of L2/L3 latency per step (warm
// L3 replays ran the same 119us as cold -> latency-, not BW-bound).
// Atomic loads cannot be duplicated or rematerialized, so the value must be
// produced at issue point and carried in VGPRs; sched_barrier(0) per step
// (kept from R3, worth -24cy/step) keeps the issue point 16 steps (~1800cy)
// ahead of the use. Compiler's own counted vmcnt then waits on nothing.
//
// Kept (verified absmax 0.0): DPP wave_shr:1 neighbor shift, lane-local
// E128, exponent-only renorm via DPP-max + readlane, wave-uniform rolling
// row byte-offset with scalar clamp.

#define CTC_C 256
#define DEP 16    // prefetch depth in steps; 3*DEP = 48 loads in flight

// non-removable, non-duplicable load; workgroup scope = fully cached
#define GLOAD(p_) \
  __hip_atomic_load((p_), __ATOMIC_RELAXED, __HIP_MEMORY_SCOPE_WORKGROUP)

// full-wave shift-right-by-1, lane 0 gets 0 (DPP wave_shr:1, bound_ctrl:0)
__device__ __forceinline__ double wshr1_f64(double x) {
  int lo = __double2loint(x), hi = __double2hiint(x);
  lo = __builtin_amdgcn_update_dpp(0, lo, 0x138, 0xf, 0xf, true);
  hi = __builtin_amdgcn_update_dpp(0, hi, 0x138, 0xf, 0xf, true);
  return __hiloint2double(hi, lo);
}

template <int CTRL>
__device__ __forceinline__ unsigned dppmax(unsigned v) {
  unsigned t = (unsigned)__builtin_amdgcn_update_dpp(0, (int)v, CTRL, 0xf, 0xf, true);
  return v > t ? v : t;
}

// Wave-uniform power-of-2 renorm. Positive doubles order by bit pattern, so
// the max of the high words carries the exponent of the wave max. All-VALU
// reduction: 4 DPP rounds within 16-lane rows, then readlane + scalar max.
__device__ __forceinline__ void renorm(double& Oa, double& Ob, double& Ea,
                                       double& Eb, double& E128, double& logC) {
  unsigned m =       (unsigned)__double2hiint(Oa);
  unsigned h;
  h = (unsigned)__double2hiint(Ob);   m = m > h ? m : h;
  h = (unsigned)__double2hiint(Ea);   m = m > h ? m : h;
  h = (unsigned)__double2hiint(Eb);   m = m > h ? m : h;
  h = (unsigned)__double2hiint(E128); m = m > h ? m : h;
  m = dppmax<0xB1>(m);    // quad_perm [1,0,3,2]  (xor 1)
  m = dppmax<0x4E>(m);    // quad_perm [2,3,0,1]  (xor 2)
  m = dppmax<0x141>(m);   // row_half_mirror      (4<->4)
  m = dppmax<0x140>(m);   // row_mirror           (8<->8): row max everywhere
  unsigned r0 = (unsigned)__builtin_amdgcn_readlane((int)m, 0);
  unsigned r1 = (unsigned)__builtin_amdgcn_readlane((int)m, 16);
  unsigned r2 = (unsigned)__builtin_amdgcn_readlane((int)m, 32);
  unsigned r3 = (unsigned)__builtin_amdgcn_readlane((int)m, 48);
  unsigned m01 = r0 > r1 ? r0 : r1;
  unsigned m23 = r2 > r3 ? r2 : r3;
  unsigned smax = m01 > m23 ? m01 : m23;
  int eb = (int)(smax >> 20);  // biased exponent of the wave max (sign bit 0)
  // scale = 2^-(eb-1022) exactly; eb==0 (all zero) => 2^1022, still exact
  double s = __hiloint2double((int)((unsigned)(2045 - eb) << 20), 0);
  Oa *= s; Ob *= s; Ea *= s; Eb *= s; E128 *= s;
  logC += (double)(eb - 1022) * 0.6931471805599453;
}

__global__ __launch_bounds__(64)
void ctc_fwd(const float* __restrict__ lp, const int* __restrict__ y,
             const int* __restrict__ ilen, const int* __restrict__ tlen,
             float* __restrict__ out, int T, int B, int S) {
  const int b = blockIdx.x;
  const int l = threadIdx.x;            // 0..63
  const size_t rowstrideF = (size_t)B * CTC_C;       // floats between rows
  const unsigned ROWB = (unsigned)(B * CTC_C * 4);   // bytes between rows

  const int len = ilen[b];              // input length, steps t=1..len-1
  const int tl  = tlen[b];              // target length

  const int ya = y[(size_t)b * S + 2 * l];
  const int yb = y[(size_t)b * S + 2 * l + 1];
  const int yprev = __shfl_up(yb, 1);   // y[2l-1] (garbage on lane 0, masked)
  const bool skipA = (l > 0) && (ya != yprev);
  const bool skipB = (yb != ya);

  // Init (t=0)
  const float* row0 = lp + (size_t)b * CTC_C;
  const int y0 = y[(size_t)b * S];
  double Ea = (l == 0) ? (double)__expf(row0[0])  : 0.;
  double Oa = (l == 0) ? (double)__expf(row0[y0]) : 0.;
  double Eb = 0., Ob = 0., E128 = 0., logC = 0.;

  // Loop-invariant per-lane element indices within a row block
  const int fA = b * CTC_C + ya;        // gathered label A
  const int fB = b * CTC_C + yb;        // gathered label B
  const int fQ = b * CTC_C;             // blank

  // ---- prime the pipeline: rows 1..DEP, slot = t & 15 ----
  float rA[DEP], rB[DEP], rQ[DEP];
#pragma unroll
  for (int t = 1; t <= DEP; ++t) {
    const float* r = lp + (size_t)t * rowstrideF;
    rA[t & 15] = GLOAD(r + fA);
    rB[t & 15] = GLOAD(r + fB);
    rQ[t & 15] = GLOAD(r + fQ);
  }

  // Rolling WAVE-UNIFORM byte offset of the refill row (row t+DEP, clamped
  // to T-1; over-reads of the last row are never consumed). Scalar-unit math.
  const unsigned capR = (unsigned)(T - 1) * ROWB;
  unsigned uoff = (unsigned)(DEP + 1) * ROWB;   // refill row for step t=1

  // One recursion step. Chunks start at t ≡ 1 (mod 16) so slots are
  // compile-time. sched_barrier(0) at the end of each step prevents the
  // machine scheduler from clustering refill loads across steps; the atomic
  // loads prevent IR-level sinking/remat (R3's failure mode).
#define CTC_STEP(i_)                                                          \
  do {                                                                        \
    const int d = (1 + (i_)) & 15;                                            \
    const double pa = (double)__expf(rA[d]);                                  \
    const double pb = (double)__expf(rB[d]);                                  \
    const double pq = (double)__expf(rQ[d]);                                  \
    {                                                                         \
      const float* rp = (const float*)((const char*)lp + uoff);               \
      rA[d] = GLOAD(rp + fA);                                                 \
      rB[d] = GLOAD(rp + fB);                                                 \
      rQ[d] = GLOAD(rp + fQ);                                                 \
      unsigned un = uoff + ROWB;                                              \
      uoff = un < capR ? un : capR;                                           \
    }                                                                         \
    const double Opm1 = wshr1_f64(Ob);      /* O[2l-1], 0 on lane 0 */        \
    const double EaOp = Ea + Opm1;                                            \
    const double EbOa = Eb + Oa;                                              \
    const double tA = skipA ? EaOp : Ea;                                      \
    const double tB = skipB ? EbOa : Eb;                                      \
    const double nOa = (Oa + tA) * pa;                                        \
    const double nOb = (Ob + tB) * pb;                                        \
    Ea = EaOp * pq;                                                           \
    Eb = EbOa * pq;                                                           \
    E128 = (E128 + Ob) * pq;                /* real only on lane 63 */        \
    Oa = nOa; Ob = nOb;                                                       \
    __builtin_amdgcn_sched_barrier(0);                                        \
  } while (0)

  const int nsteps = len - 1;           // steps t = 1..nsteps (len >= 768)
  const int nch = nsteps >> 4;          // full 16-step chunks
  const int rem = nsteps & 15;

  for (int c = 0; c < nch; ++c) {
#pragma unroll
    for (int i = 0; i < 16; ++i) {
      CTC_STEP(i);
      if ((i & 7) == 7) renorm(Oa, Ob, Ea, Eb, E128, logC);
    }
  }
  if (rem) {                            // guarded tail chunk (wave-uniform)
#pragma unroll
    for (int i = 0; i < 16; ++i) {
      if (i < rem) {
        CTC_STEP(i);
        if ((i & 7) == 7) renorm(Oa, Ob, Ea, Eb, E128, logC);
      }
    }
  }
#undef CTC_STEP

  // Final: ll = logC + log(alpha_exp[2*tl] + alpha_exp[2*tl-1])
  double vEa = __shfl(Ea, (tl >> 1) & 63);
  double vEb = __shfl(Eb, (tl >> 1) & 63);
  double vE128 = __shfl(E128, 63);      // the one real E[128]
  double vhi = (tl == S) ? vE128 : ((tl & 1) ? vEb : vEa);
  const int s2 = tl - 1;
  double vOa = __shfl(Oa, (s2 >> 1) & 63);
  double vOb = __shfl(Ob, (s2 >> 1) & 63);
  double vlo = (s2 & 1) ? vOb : vOa;

  double sum = vhi + vlo;
  double loss;
  if (sum > 0.) {
    loss = -(logC + log(sum));
  } else {
    loss = 1e30;                        // -inf likelihood
  }
  if (!(loss < 5.0e8)) loss = 0.;       // zero_infinity (catches inf/NaN)
  float contrib = (float)(loss / (double)tl / (double)B);
  if (l == 0) atomicAdd(out, contrib);
}

extern "C" void kernel_launch(void* const* d_in, const int* in_sizes, int n_in,
                              void* d_out, int out_size, void* d_ws, size_t ws_size,
                              hipStream_t stream) {
  const float* lp   = (const float*)d_in[0];
  const int*   yy   = (const int*)d_in[1];
  const int*   ilen = (const int*)d_in[2];
  const int*   tlen = (const int*)d_in[3];
  float* out = (float*)d_out;

  int B = in_sizes[2];
  int S = in_sizes[1] / B;
  int T = in_sizes[0] / (B * CTC_C);

  hipMemsetAsync(out, 0, sizeof(float), stream);
  ctc_fwd<<<B, 64, 0, stream>>>(lp, yy, ilen, tlen, out, T, B, S);
}

// Round 5
// 258.742 us; speedup vs baseline: 1.0389x; 1.0389x over previous
//
#include <hip/hip_runtime.h>

// CTC loss forward, T=1024, B=128, C=256, S=128, L=2S+1=257.
// One wave (64 lanes) per batch. Lane l owns odd states O[2l],O[2l+1]
// (labels y[2l],y[2l+1]) and blank states E[2l],E[2l+1]; E[128] kept
// LANE-LOCAL (only lane 63's copy is real; broadcast once at the end).
// Exp-domain recursion in FP64 with exact power-of-2 renorm every 8 steps.
//
// R5: kill the divergent VMEM gathers. Evidence: R1(resident,72VGPR)=135us,
// R3(collapsed,48VGPR)=119.5us, R4(atomic,60VGPR)=126.5us, and R3's warm-L3
// replays (FETCH=4KB) ran the same speed as cold -> the ~180cy/step stall is
// independent of pipeline depth AND cache level. That fingerprints gather
// ADDRESS-PROCESSING occupancy in the per-CU memory pipe (2 wave64 gathers
// with per-lane label addresses), not load latency. Fix:
//   - stage whole 1KB rows via ONE coalesced global_load_lds_dwordx4/step
//     (lane i = bytes 16i..16i+15) into a 16-slot LDS ring (16KB);
//   - gather ya/yb/blank with 3 ds_read_b32 (random labels over 32 banks
//     ~2-way conflict = free per m136; blank is a broadcast);
//   - manual s_waitcnt vmcnt(14) + sched_barrier(0) covers the DMA->ds_read
//     hazard the compiler can't see (vmcnt retires in order; only our GLLs
//     live in the loop, drained to 0 before priming; 14 = 16-ring minus
//     2-step ds prefetch lead);
//   - ds_reads prefetched 2 steps (~220cy) ahead in a depth-2 reg ring
//     (covers ~120cy LDS latency). Consume-before-fill body order makes the
//     slot t / t+16 reuse race-free (consumer's lgkm wait precedes GLL).
//
// Kept (verified absmax 0.0 twice): DPP wave_shr:1 neighbor shift,
// lane-local E128, exponent-only renorm via DPP-max + readlane,
// wave-uniform rolling row byte-offset, per-step sched_barrier(0).

#define CTC_C 256
#define RING 16    // LDS ring depth (rows); GLL lead = 16 steps
#define PFD  2     // ds-read prefetch lead (steps)

typedef unsigned int u32;

// one coalesced row-stage: lane i pulls 16B at g+16i into lds_base+16i
__device__ __forceinline__ void gll16(const void* g, void* l) {
  __builtin_amdgcn_global_load_lds(
      (const __attribute__((address_space(1))) u32*)g,
      (__attribute__((address_space(3))) u32*)l, 16, 0, 0);
}

// full-wave shift-right-by-1, lane 0 gets 0 (DPP wave_shr:1, bound_ctrl:0)
__device__ __forceinline__ double wshr1_f64(double x) {
  int lo = __double2loint(x), hi = __double2hiint(x);
  lo = __builtin_amdgcn_update_dpp(0, lo, 0x138, 0xf, 0xf, true);
  hi = __builtin_amdgcn_update_dpp(0, hi, 0x138, 0xf, 0xf, true);
  return __hiloint2double(hi, lo);
}

template <int CTRL>
__device__ __forceinline__ unsigned dppmax(unsigned v) {
  unsigned t = (unsigned)__builtin_amdgcn_update_dpp(0, (int)v, CTRL, 0xf, 0xf, true);
  return v > t ? v : t;
}

// Wave-uniform power-of-2 renorm. Positive doubles order by bit pattern, so
// the max of the high words carries the exponent of the wave max. All-VALU
// reduction: 4 DPP rounds within 16-lane rows, then readlane + scalar max.
__device__ __forceinline__ void renorm(double& Oa, double& Ob, double& Ea,
                                       double& Eb, double& E128, double& logC) {
  unsigned m =       (unsigned)__double2hiint(Oa);
  unsigned h;
  h = (unsigned)__double2hiint(Ob);   m = m > h ? m : h;
  h = (unsigned)__double2hiint(Ea);   m = m > h ? m : h;
  h = (unsigned)__double2hiint(Eb);   m = m > h ? m : h;
  h = (unsigned)__double2hiint(E128); m = m > h ? m : h;
  m = dppmax<0xB1>(m);    // quad_perm [1,0,3,2]  (xor 1)
  m = dppmax<0x4E>(m);    // quad_perm [2,3,0,1]  (xor 2)
  m = dppmax<0x141>(m);   // row_half_mirror      (4<->4)
  m = dppmax<0x140>(m);   // row_mirror           (8<->8): row max everywhere
  unsigned r0 = (unsigned)__builtin_amdgcn_readlane((int)m, 0);
  unsigned r1 = (unsigned)__builtin_amdgcn_readlane((int)m, 16);
  unsigned r2 = (unsigned)__builtin_amdgcn_readlane((int)m, 32);
  unsigned r3 = (unsigned)__builtin_amdgcn_readlane((int)m, 48);
  unsigned m01 = r0 > r1 ? r0 : r1;
  unsigned m23 = r2 > r3 ? r2 : r3;
  unsigned smax = m01 > m23 ? m01 : m23;
  int eb = (int)(smax >> 20);  // biased exponent of the wave max (sign bit 0)
  // scale = 2^-(eb-1022) exactly; eb==0 (all zero) => 2^1022, still exact
  double s = __hiloint2double((int)((unsigned)(2045 - eb) << 20), 0);
  Oa *= s; Ob *= s; Ea *= s; Eb *= s; E128 *= s;
  logC += (double)(eb - 1022) * 0.6931471805599453;
}

__global__ __launch_bounds__(64)
void ctc_fwd(const float* __restrict__ lp, const int* __restrict__ y,
             const int* __restrict__ ilen, const int* __restrict__ tlen,
             float* __restrict__ out, int T, int B, int S) {
  __shared__ __align__(16) float ring[RING][CTC_C];   // 16KB row ring

  const int b = blockIdx.x;
  const int l = threadIdx.x;            // 0..63
  const unsigned ROWB = (unsigned)(B * CTC_C * 4);   // bytes between rows

  const int len = ilen[b];              // input length, steps t=1..len-1
  const int tl  = tlen[b];              // target length

  const int ya = y[(size_t)b * S + 2 * l];
  const int yb = y[(size_t)b * S + 2 * l + 1];
  const int yprev = __shfl_up(yb, 1);   // y[2l-1] (garbage on lane 0, masked)
  const bool skipA = (l > 0) && (ya != yprev);
  const bool skipB = (yb != ya);

  // Init (t=0)
  const float* row0 = lp + (size_t)b * CTC_C;
  const int y0 = y[(size_t)b * S];
  double Ea = (l == 0) ? (double)__expf(row0[0])  : 0.;
  double Oa = (l == 0) ? (double)__expf(row0[y0]) : 0.;
  double Eb = 0., Ob = 0., E128 = 0., logC = 0.;

  // per-lane global byte pointer: lane i owns bytes 16i..16i+15 of b's row
  const char* gLane = (const char*)lp + (size_t)b * CTC_C * 4 + 16 * (size_t)l;

  // drain prologue VMEM so vmcnt counts only our row-stages
  asm volatile("s_waitcnt vmcnt(0)" ::: "memory");
  __builtin_amdgcn_sched_barrier(0);

  // prime the LDS ring with rows 1..16 (len >= 768, always valid)
#pragma unroll
  for (int t = 1; t <= RING; ++t)
    gll16(gLane + (size_t)t * ROWB, &ring[t & 15][0]);
  asm volatile("s_waitcnt vmcnt(0)" ::: "memory");
  __builtin_amdgcn_sched_barrier(0);

  // prime the depth-2 ds-read prefetch regs with rows 1 (slot t&1=1) and 2
  float pfA[2], pfB[2], pfQ[2];
  pfA[1] = ring[1][ya]; pfB[1] = ring[1][yb]; pfQ[1] = ring[1][0];
  pfA[0] = ring[2][ya]; pfB[0] = ring[2][yb]; pfQ[0] = ring[2][0];

  // rolling WAVE-UNIFORM byte offset of the stage row (row t+16, clamped to
  // T-1; clamped over-stages are never consumed — race-free, see header)
  const unsigned capR = (unsigned)(T - 1) * ROWB;
  unsigned uoff = (unsigned)(RING + 1) * ROWB;     // stage row for step t=1

  // One step (t = chunk_base + 1 + i_). Body order matters:
  //  consume pf (lgkm wait lands here) -> stage row t+16 into slot t&15 ->
  //  vmcnt(14) (=> GLL(t+2) retired; in-order) -> ds_read row t+2 -> f64.
#define CTC_STEP(i_)                                                          \
  do {                                                                        \
    const int dp = (1 + (i_)) & 1;          /* pf slot for row t   */         \
    const int sl = (3 + (i_)) & 15;         /* LDS slot of row t+2 */         \
    const int sg = (1 + (i_)) & 15;         /* LDS slot for row t+16 */       \
    const double pa = (double)__expf(pfA[dp]);                                \
    const double pb = (double)__expf(pfB[dp]);                                \
    const double pq = (double)__expf(pfQ[dp]);                                \
    gll16(gLane + uoff, &ring[sg][0]);                                        \
    {                                                                         \
      unsigned un = uoff + ROWB;                                              \
      uoff = un < capR ? un : capR;                                           \
    }                                                                         \
    asm volatile("s_waitcnt vmcnt(14)" ::: "memory");                         \
    __builtin_amdgcn_sched_barrier(0);                                        \
    pfA[dp] = ring[sl][ya];                                                   \
    pfB[dp] = ring[sl][yb];                                                   \
    pfQ[dp] = ring[sl][0];                                                    \
    const double Opm1 = wshr1_f64(Ob);      /* O[2l-1], 0 on lane 0 */        \
    const double EaOp = Ea + Opm1;                                            \
    const double EbOa = Eb + Oa;                                              \
    const double tA = skipA ? EaOp : Ea;                                      \
    const double tB = skipB ? EbOa : Eb;                                      \
    const double nOa = (Oa + tA) * pa;                                        \
    const double nOb = (Ob + tB) * pb;                                        \
    Ea = EaOp * pq;                                                           \
    Eb = EbOa * pq;                                                           \
    E128 = (E128 + Ob) * pq;                /* real only on lane 63 */        \
    Oa = nOa; Ob = nOb;                                                       \
    __builtin_amdgcn_sched_barrier(0);                                        \
  } while (0)

  const int nsteps = len - 1;           // steps t = 1..nsteps (len >= 768)
  const int nch = nsteps >> 4;          // full 16-step chunks
  const int rem = nsteps & 15;

  for (int c = 0; c < nch; ++c) {
#pragma unroll
    for (int i = 0; i < 16; ++i) {
      CTC_STEP(i);
      if ((i & 7) == 7) renorm(Oa, Ob, Ea, Eb, E128, logC);
    }
  }
  if (rem) {                            // guarded tail chunk (wave-uniform)
#pragma unroll
    for (int i = 0; i < 16; ++i) {
      if (i < rem) {
        CTC_STEP(i);
        if ((i & 7) == 7) renorm(Oa, Ob, Ea, Eb, E128, logC);
      }
    }
  }
#undef CTC_STEP

  // Final: ll = logC + log(alpha_exp[2*tl] + alpha_exp[2*tl-1])
  double vEa = __shfl(Ea, (tl >> 1) & 63);
  double vEb = __shfl(Eb, (tl >> 1) & 63);
  double vE128 = __shfl(E128, 63);      // the one real E[128]
  double vhi = (tl == S) ? vE128 : ((tl & 1) ? vEb : vEa);
  const int s2 = tl - 1;
  double vOa = __shfl(Oa, (s2 >> 1) & 63);
  double vOb = __shfl(Ob, (s2 >> 1) & 63);
  double vlo = (s2 & 1) ? vOb : vOa;

  double sum = vhi + vlo;
  double loss;
  if (sum > 0.) {
    loss = -(logC + log(sum));
  } else {
    loss = 1e30;                        // -inf likelihood
  }
  if (!(loss < 5.0e8)) loss = 0.;       // zero_infinity (catches inf/NaN)
  float contrib = (float)(loss / (double)tl / (double)B);
  if (l == 0) atomicAdd(out, contrib);
}

extern "C" void kernel_launch(void* const* d_in, const int* in_sizes, int n_in,
                              void* d_out, int out_size, void* d_ws, size_t ws_size,
                              hipStream_t stream) {
  const float* lp   = (const float*)d_in[0];
  const int*   yy   = (const int*)d_in[1];
  const int*   ilen = (const int*)d_in[2];
  const int*   tlen = (const int*)d_in[3];
  float* out = (float*)d_out;

  int B = in_sizes[2];
  int S = in_sizes[1] / B;
  int T = in_sizes[0] / (B * CTC_C);

  hipMemsetAsync(out, 0, sizeof(float), stream);
  ctc_fwd<<<B, 64, 0, stream>>>(lp, yy, ilen, tlen, out, T, B, S);
}

// Round 6
// 250.606 us; speedup vs baseline: 1.0726x; 1.0325x over previous
//
#include <hip/hip_runtime.h>

// CTC loss forward, T=1024, B=128, C=256, S=128, L=2S+1=257.
// One wave (64 lanes) per batch. Lane l owns odd states O[2l],O[2l+1]
// (labels y[2l],y[2l+1]) and blank states E[2l],E[2l+1]; E[128] kept
// LANE-LOCAL (only lane 63's copy is real; broadcast once at the end).
// Exp-domain recursion in FP64 with exact power-of-2 renorm.
//
// R6: de-serialize the step. R2-R5 proved the loop is NOT memory-bound
// (cold==warm-L3 time; gathers vs coalesced GLL ~ equal). The ~170cy/step
// non-VALU stall is the in-step chain exp->cvt->f64-tree exposed by 1
// wave/SIMD in-order issue + per-step sched_barrier walls. Changes:
//  - exp-early: probabilities for step t are exp'd at step t-1 from the
//    LDS-prefetch regs (pf ring of 4, ds_read lead 4 steps); the step's
//    critical path starts at ready f64 regs.
//  - walls removed except ONE sched_barrier after vmcnt (rule #18);
//    memory ops stay pinned by the vmcnt asm fences (memory clobber),
//    VALU flows across step boundaries.
//  - renorm every 16 steps (pow2 renorm is EXACT; only margin matters:
//    400-nat spread + <=16*12-nat decay << 708) and finished with
//    row_bcast15/31 DPP + a single readlane (was 4 readlane roundtrips).
//  - vmcnt(12): need row t+4 retired; rows t+5..t+16 (12) may be in flight.
//
// Kept from R5 (verified absmax 0.0): GLL row staging into a 16-slot LDS
// ring, ds_read label gathers, DPP wave_shr:1 shift, lane-local E128,
// exponent-only renorm, wave-uniform rolling row offset.

#define CTC_C 256
#define RING 16    // LDS ring depth (rows); GLL lead = 16 steps

typedef unsigned int u32;

// one coalesced row-stage: lane i pulls 16B at g+16i into lds_base+16i
__device__ __forceinline__ void gll16(const void* g, void* l) {
  __builtin_amdgcn_global_load_lds(
      (const __attribute__((address_space(1))) u32*)g,
      (__attribute__((address_space(3))) u32*)l, 16, 0, 0);
}

// full-wave shift-right-by-1, lane 0 gets 0 (DPP wave_shr:1, bound_ctrl:0)
__device__ __forceinline__ double wshr1_f64(double x) {
  int lo = __double2loint(x), hi = __double2hiint(x);
  lo = __builtin_amdgcn_update_dpp(0, lo, 0x138, 0xf, 0xf, true);
  hi = __builtin_amdgcn_update_dpp(0, hi, 0x138, 0xf, 0xf, true);
  return __hiloint2double(hi, lo);
}

template <int CTRL>
__device__ __forceinline__ unsigned dppmax(unsigned v) {
  unsigned t = (unsigned)__builtin_amdgcn_update_dpp(0, (int)v, CTRL, 0xf, 0xf, true);
  return v > t ? v : t;
}

// Wave-uniform power-of-2 renorm. Positive doubles order by bit pattern, so
// the max of the high words carries the exponent of the wave max. All-VALU:
// 4 DPP rounds (16-lane row max) + row_bcast15 + row_bcast31 (lane 63 has
// the global max) + ONE readlane.
__device__ __forceinline__ void renorm(double& Oa, double& Ob, double& Ea,
                                       double& Eb, double& E128, double& logC) {
  unsigned m =       (unsigned)__double2hiint(Oa);
  unsigned h;
  h = (unsigned)__double2hiint(Ob);   m = m > h ? m : h;
  h = (unsigned)__double2hiint(Ea);   m = m > h ? m : h;
  h = (unsigned)__double2hiint(Eb);   m = m > h ? m : h;
  h = (unsigned)__double2hiint(E128); m = m > h ? m : h;
  m = dppmax<0xB1>(m);    // quad_perm [1,0,3,2]  (xor 1)
  m = dppmax<0x4E>(m);    // quad_perm [2,3,0,1]  (xor 2)
  m = dppmax<0x141>(m);   // row_half_mirror      (4<->4)
  m = dppmax<0x140>(m);   // row_mirror           (8<->8): row max everywhere
  m = dppmax<0x142>(m);   // row_bcast15: lanes16-31|=row0, lanes48-63|=row2
  m = dppmax<0x143>(m);   // row_bcast31: lanes32-63 |= max(row0,row1)
  unsigned smax = (unsigned)__builtin_amdgcn_readlane((int)m, 63);
  int eb = (int)(smax >> 20);  // biased exponent of the wave max (sign bit 0)
  // scale = 2^-(eb-1022) exactly; eb==0 (all zero) => 2^1022, still exact
  double s = __hiloint2double((int)((unsigned)(2045 - eb) << 20), 0);
  Oa *= s; Ob *= s; Ea *= s; Eb *= s; E128 *= s;
  logC += (double)(eb - 1022) * 0.6931471805599453;
}

__global__ __launch_bounds__(64)
void ctc_fwd(const float* __restrict__ lp, const int* __restrict__ y,
             const int* __restrict__ ilen, const int* __restrict__ tlen,
             float* __restrict__ out, int T, int B, int S) {
  __shared__ __align__(16) float ring[RING][CTC_C];   // 16KB row ring

  const int b = blockIdx.x;
  const int l = threadIdx.x;            // 0..63
  const unsigned ROWB = (unsigned)(B * CTC_C * 4);   // bytes between rows

  const int len = ilen[b];              // input length, steps t=1..len-1
  const int tl  = tlen[b];              // target length

  const int ya = y[(size_t)b * S + 2 * l];
  const int yb = y[(size_t)b * S + 2 * l + 1];
  const int yprev = __shfl_up(yb, 1);   // y[2l-1] (garbage on lane 0, masked)
  const bool skipA = (l > 0) && (ya != yprev);
  const bool skipB = (yb != ya);

  // Init (t=0)
  const float* row0 = lp + (size_t)b * CTC_C;
  const int y0 = y[(size_t)b * S];
  double Ea = (l == 0) ? (double)__expf(row0[0])  : 0.;
  double Oa = (l == 0) ? (double)__expf(row0[y0]) : 0.;
  double Eb = 0., Ob = 0., E128 = 0., logC = 0.;

  // per-lane global byte pointer: lane i owns bytes 16i..16i+15 of b's row
  const char* gLane = (const char*)lp + (size_t)b * CTC_C * 4 + 16 * (size_t)l;

  // drain prologue VMEM so vmcnt counts only our row-stages
  asm volatile("s_waitcnt vmcnt(0)" ::: "memory");
  __builtin_amdgcn_sched_barrier(0);

  // prime the LDS ring with rows 1..16 (len >= 768, always valid)
#pragma unroll
  for (int t = 1; t <= RING; ++t)
    gll16(gLane + (size_t)t * ROWB, &ring[t & 15][0]);
  asm volatile("s_waitcnt vmcnt(0)" ::: "memory");
  __builtin_amdgcn_sched_barrier(0);

  // pf ring (4 deep): rows 1..4 in slots 1,2,3,0  (slot = row & 3)
  float pfA[4], pfB[4], pfQ[4];
#pragma unroll
  for (int t = 1; t <= 4; ++t) {
    pfA[t & 3] = ring[t & 15][ya];
    pfB[t & 3] = ring[t & 15][yb];
    pfQ[t & 3] = ring[t & 15][0];
  }
  // e ring (2 deep): exp'd probabilities, slot = row & 1. Prime row 1.
  double eA2[2], eB2[2], eQ2[2];
  eA2[1] = (double)__expf(pfA[1]);
  eB2[1] = (double)__expf(pfB[1]);
  eQ2[1] = (double)__expf(pfQ[1]);

  // rolling WAVE-UNIFORM byte offset of the stage row (row t+16, clamped to
  // T-1; clamped over-stages are never consumed)
  const unsigned capR = (unsigned)(T - 1) * ROWB;
  unsigned uoff = (unsigned)(RING + 1) * ROWB;     // stage row for step t=1

  // Step t = chunk_base + 1 + i_:
  //  consume e[t&1] -> f64 update; build e[(t+1)&1] from pf[(t+1)&3];
  //  GLL row t+16 -> slot t&15; vmcnt(12) => row t+4 retired; SB(0);
  //  ds_read row t+4 -> pf[(t+4)&3]. No step-end wall: VALU flows across
  //  steps; memory ops are fenced per-step by the vmcnt asm.
#define CTC_STEP(i_)                                                          \
  do {                                                                        \
    const int eu = (1 + (i_)) & 1;          /* e slot for row t        */     \
    const int en = (2 + (i_)) & 1;          /* e slot for row t+1      */     \
    const int pn = (2 + (i_)) & 3;          /* pf slot of row t+1      */     \
    const int pr = (5 + (i_)) & 3;          /* pf slot for row t+4     */     \
    const int sl = (5 + (i_)) & 15;         /* LDS slot of row t+4     */     \
    const int sg = (1 + (i_)) & 15;         /* LDS slot for row t+16   */     \
    const double pa = eA2[eu], pb = eB2[eu], pq = eQ2[eu];                    \
    eA2[en] = (double)__expf(pfA[pn]);                                        \
    eB2[en] = (double)__expf(pfB[pn]);                                        \
    eQ2[en] = (double)__expf(pfQ[pn]);                                        \
    gll16(gLane + uoff, &ring[sg][0]);                                        \
    {                                                                         \
      unsigned un = uoff + ROWB;                                              \
      uoff = un < capR ? un : capR;                                           \
    }                                                                         \
    asm volatile("s_waitcnt vmcnt(12)" ::: "memory");                         \
    __builtin_amdgcn_sched_barrier(0);                                        \
    pfA[pr] = ring[sl][ya];                                                   \
    pfB[pr] = ring[sl][yb];                                                   \
    pfQ[pr] = ring[sl][0];                                                    \
    const double Opm1 = wshr1_f64(Ob);      /* O[2l-1], 0 on lane 0 */        \
    const double EaOp = Ea + Opm1;                                            \
    const double EbOa = Eb + Oa;                                              \
    const double tA = skipA ? EaOp : Ea;                                      \
    const double tB = skipB ? EbOa : Eb;                                      \
    const double nOa = (Oa + tA) * pa;                                        \
    const double nOb = (Ob + tB) * pb;                                        \
    Ea = EaOp * pq;                                                           \
    Eb = EbOa * pq;                                                           \
    E128 = (E128 + Ob) * pq;                /* real only on lane 63 */        \
    Oa = nOa; Ob = nOb;                                                       \
  } while (0)

  const int nsteps = len - 1;           // steps t = 1..nsteps (len >= 768)
  const int nch = nsteps >> 4;          // full 16-step chunks
  const int rem = nsteps & 15;

  for (int c = 0; c < nch; ++c) {
#pragma unroll
    for (int i = 0; i < 16; ++i) {
      CTC_STEP(i);
      if (i == 15) renorm(Oa, Ob, Ea, Eb, E128, logC);
    }
  }
  if (rem) {                            // guarded tail chunk (wave-uniform)
#pragma unroll
    for (int i = 0; i < 16; ++i) {
      if (i < rem) CTC_STEP(i);         // <=15 extra steps: f64 margin ok
    }
  }
#undef CTC_STEP

  // Final: ll = logC + log(alpha_exp[2*tl] + alpha_exp[2*tl-1])
  double vEa = __shfl(Ea, (tl >> 1) & 63);
  double vEb = __shfl(Eb, (tl >> 1) & 63);
  double vE128 = __shfl(E128, 63);      // the one real E[128]
  double vhi = (tl == S) ? vE128 : ((tl & 1) ? vEb : vEa);
  const int s2 = tl - 1;
  double vOa = __shfl(Oa, (s2 >> 1) & 63);
  double vOb = __shfl(Ob, (s2 >> 1) & 63);
  double vlo = (s2 & 1) ? vOb : vOa;

  double sum = vhi + vlo;
  double loss;
  if (sum > 0.) {
    loss = -(logC + log(sum));
  } else {
    loss = 1e30;                        // -inf likelihood
  }
  if (!(loss < 5.0e8)) loss = 0.;       // zero_infinity (catches inf/NaN)
  float contrib = (float)(loss / (double)tl / (double)B);
  if (l == 0) atomicAdd(out, contrib);
}

extern "C" void kernel_launch(void* const* d_in, const int* in_sizes, int n_in,
                              void* d_out, int out_size, void* d_ws, size_t ws_size,
                              hipStream_t stream) {
  const float* lp   = (const float*)d_in[0];
  const int*   yy   = (const int*)d_in[1];
  const int*   ilen = (const int*)d_in[2];
  const int*   tlen = (const int*)d_in[3];
  float* out = (float*)d_out;

  int B = in_sizes[2];
  int S = in_sizes[1] / B;
  int T = in_sizes[0] / (B * CTC_C);

  hipMemsetAsync(out, 0, sizeof(float), stream);
  ctc_fwd<<<B, 64, 0, stream>>>(lp, yy, ilen, tlen, out, T, B, S);
}